// Round 2
// baseline (770.897 us; speedup 1.0000x reference)
//
#include <hip/hip_runtime.h>
#include <hip/hip_bf16.h>

typedef __bf16 bf16_t;
typedef __bf16 bf16x4 __attribute__((ext_vector_type(4)));
typedef __bf16 bf16x8 __attribute__((ext_vector_type(8)));
typedef float f32x4 __attribute__((ext_vector_type(4)));

#define IGNORE_INDEX (-100)
#define N_ROWS 4096
#define H_DIM  1024
#define V_DIM  32000

#define BM 128
#define BN 128
#define BK 32
#define CT_NUM (V_DIM / BN)   /* 250 */
#define RT_NUM (N_ROWS / BM)  /* 32 */

// ---------------- cast x: fp32 -> bf16, flat ----------------
__global__ __launch_bounds__(256) void k_cast_x(const float* __restrict__ in,
                                                bf16_t* __restrict__ out) {
  int i = (blockIdx.x * 256 + threadIdx.x) * 4;
  float4 v = *(const float4*)(in + i);
  bf16x4 o = { (bf16_t)v.x, (bf16_t)v.y, (bf16_t)v.z, (bf16_t)v.w };
  *(bf16x4*)(out + i) = o;
}

// ------------- transpose-cast weight: [H,V] fp32 -> [V,H] bf16 -------------
// 64x64 tile: float4 reads (256B/row), bf16x8 writes (128B/row).
#define TK 64
#define TV 64
__global__ __launch_bounds__(256) void k_cast_wT(const float* __restrict__ w,
                                                 bf16_t* __restrict__ wT) {
  __shared__ float tile[TK][TV + 1];
  const int v0 = blockIdx.x * TV;
  const int k0 = blockIdx.y * TK;
  const int t = threadIdx.x;
  {
    const int vq = t & 15;        // float4 index within row
    const int kr0 = t >> 4;       // 0..15
#pragma unroll
    for (int r = 0; r < TK; r += 16) {
      float4 v = *(const float4*)(w + (size_t)(k0 + kr0 + r) * V_DIM + v0 + vq * 4);
      tile[kr0 + r][vq * 4 + 0] = v.x;
      tile[kr0 + r][vq * 4 + 1] = v.y;
      tile[kr0 + r][vq * 4 + 2] = v.z;
      tile[kr0 + r][vq * 4 + 3] = v.w;
    }
  }
  __syncthreads();
  {
    const int kq = t & 7;         // bf16x8 index within k-row
    const int vr0 = t >> 3;       // 0..31
#pragma unroll
    for (int r = 0; r < TV; r += 32) {
      bf16x8 o;
#pragma unroll
      for (int j = 0; j < 8; ++j)
        o[j] = (bf16_t)tile[kq * 8 + j][vr0 + r];
      *(bf16x8*)(wT + (size_t)(v0 + vr0 + r) * H_DIM + k0 + kq * 8) = o;
    }
  }
}

// ------------- fused GEMM tile + per-row max/sumexp partials -------------
// LDS tiles are stored in FRAGMENT-LINEAR order: 16B slot s <-> (row-group
// g=s>>6, quad=(s>>4)&3, r15=s&15), holding global (row=g*16+r15,
// k=quad*8..quad*8+7). global_load_lds writes slot = lane index (contiguous);
// fragment ds_read_b128 of wave = 1KiB contiguous -> zero bank conflicts.
__global__ __launch_bounds__(256) void k_gemm_lse(const bf16_t* __restrict__ A,
                                                  const bf16_t* __restrict__ Bt,
                                                  float* __restrict__ m_part,
                                                  float* __restrict__ s_part) {
  __shared__ __align__(16) bf16_t sA[BM * BK];
  __shared__ __align__(16) bf16_t sB[BN * BK];
  __shared__ float maxbuf[BM][2];
  __shared__ float sumbuf[BM][2];

  const int tid = threadIdx.x;
  const int rt = blockIdx.x;   // 0..31  row tile (FAST dim -> per-XCD A stays hot)
  const int ct = blockIdx.y;   // 0..249 column tile
  const int m0 = rt * BM;
  const int n0 = ct * BN;

  const int w = tid >> 6;
  const int l = tid & 63;
  const int wr = w >> 1, wc = w & 1;
  const int quad = l >> 4, lc = l & 15;

  f32x4 acc[4][4];
#pragma unroll
  for (int i = 0; i < 4; ++i)
#pragma unroll
    for (int j = 0; j < 4; ++j)
      acc[i][j] = (f32x4){0.f, 0.f, 0.f, 0.f};

  // staging slot -> (row, kcol) for fragment-linear layout
  const int row0 = ((tid >> 6) << 4) + (tid & 15);   // slots 0..255
  const int kc0  = ((tid >> 4) & 3) * 8;
  const int row1 = row0 + 64;                        // slots 256..511

  const bf16_t* a0 = A + (size_t)(m0 + row0) * H_DIM + kc0;
  const bf16_t* a1 = A + (size_t)(m0 + row1) * H_DIM + kc0;
  const bf16_t* b0 = Bt + (size_t)(n0 + row0) * H_DIM + kc0;
  const bf16_t* b1 = Bt + (size_t)(n0 + row1) * H_DIM + kc0;
  bf16_t* dA0 = sA + (size_t)tid * 8;
  bf16_t* dA1 = sA + (size_t)(tid + 256) * 8;
  bf16_t* dB0 = sB + (size_t)tid * 8;
  bf16_t* dB1 = sB + (size_t)(tid + 256) * 8;

  for (int kt = 0; kt < H_DIM / BK; ++kt) {
    __syncthreads();  // previous iter's ds_reads done before overwrite
    __builtin_amdgcn_global_load_lds((const __attribute__((address_space(1))) void*)a0,
                                     (__attribute__((address_space(3))) void*)dA0, 16, 0, 0);
    __builtin_amdgcn_global_load_lds((const __attribute__((address_space(1))) void*)a1,
                                     (__attribute__((address_space(3))) void*)dA1, 16, 0, 0);
    __builtin_amdgcn_global_load_lds((const __attribute__((address_space(1))) void*)b0,
                                     (__attribute__((address_space(3))) void*)dB0, 16, 0, 0);
    __builtin_amdgcn_global_load_lds((const __attribute__((address_space(1))) void*)b1,
                                     (__attribute__((address_space(3))) void*)dB1, 16, 0, 0);
    a0 += BK; a1 += BK; b0 += BK; b1 += BK;
    __syncthreads();  // drains vmcnt for all waves

    bf16x8 a_frag[4], b_frag[4];
#pragma unroll
    for (int i = 0; i < 4; ++i)
      a_frag[i] = *(const bf16x8*)(sA + (size_t)(((wr * 4 + i) << 6) + l) * 8);
#pragma unroll
    for (int j = 0; j < 4; ++j)
      b_frag[j] = *(const bf16x8*)(sB + (size_t)(((wc * 4 + j) << 6) + l) * 8);
#pragma unroll
    for (int i = 0; i < 4; ++i)
#pragma unroll
      for (int j = 0; j < 4; ++j)
        acc[i][j] = __builtin_amdgcn_mfma_f32_16x16x32_bf16(a_frag[i], b_frag[j], acc[i][j], 0, 0, 0);
  }

  // C/D layout: col = lane&15 (N-dim), row = quad*4 + reg (M-dim).
  // Global row of acc[i][*][r] = m0 + wr*64 + i*16 + quad*4 + r
  float rmax[4][4];
#pragma unroll
  for (int i = 0; i < 4; ++i)
#pragma unroll
    for (int r = 0; r < 4; ++r) {
      float mx = fmaxf(fmaxf(acc[i][0][r], acc[i][1][r]),
                       fmaxf(acc[i][2][r], acc[i][3][r]));
#pragma unroll
      for (int off = 1; off < 16; off <<= 1)
        mx = fmaxf(mx, __shfl_xor(mx, off, 64));
      rmax[i][r] = mx;
    }
  __syncthreads();
  if (lc == 0) {
#pragma unroll
    for (int i = 0; i < 4; ++i)
#pragma unroll
      for (int r = 0; r < 4; ++r)
        maxbuf[wr * 64 + i * 16 + quad * 4 + r][wc] = rmax[i][r];
  }
  __syncthreads();
  float rowmax[4][4];
#pragma unroll
  for (int i = 0; i < 4; ++i)
#pragma unroll
    for (int r = 0; r < 4; ++r) {
      int row = wr * 64 + i * 16 + quad * 4 + r;
      rowmax[i][r] = fmaxf(maxbuf[row][0], maxbuf[row][1]);
    }
#pragma unroll
  for (int i = 0; i < 4; ++i)
#pragma unroll
    for (int r = 0; r < 4; ++r) {
      float s = __expf(acc[i][0][r] - rowmax[i][r]) + __expf(acc[i][1][r] - rowmax[i][r]) +
                __expf(acc[i][2][r] - rowmax[i][r]) + __expf(acc[i][3][r] - rowmax[i][r]);
#pragma unroll
      for (int off = 1; off < 16; off <<= 1)
        s += __shfl_xor(s, off, 64);
      if (lc == 0) sumbuf[wr * 64 + i * 16 + quad * 4 + r][wc] = s;
    }
  __syncthreads();
  if (wc == 0 && lc == 0) {
#pragma unroll
    for (int i = 0; i < 4; ++i)
#pragma unroll
      for (int r = 0; r < 4; ++r) {
        int row = wr * 64 + i * 16 + quad * 4 + r;
        size_t idx = (size_t)(m0 + row) * CT_NUM + ct;
        m_part[idx] = rowmax[i][r];
        s_part[idx] = sumbuf[row][0] + sumbuf[row][1];
      }
  }
}

// ------------- combine partials + target logit -> per-block partial sums ----
__global__ __launch_bounds__(256) void k_combine(const float* __restrict__ x,
                                                 const bf16_t* __restrict__ wT,
                                                 const int* __restrict__ target,
                                                 const float* __restrict__ m_part,
                                                 const float* __restrict__ s_part,
                                                 float* __restrict__ blk_part) {
  __shared__ float red[8];
  const int wv = threadIdx.x >> 6;
  const int row = blockIdx.x * 4 + wv;  // one wave per row
  const int l = threadIdx.x & 63;
  float m = -INFINITY, s = 0.f;
  for (int ctb = l; ctb < CT_NUM; ctb += 64) {
    float mj = m_part[(size_t)row * CT_NUM + ctb];
    float sj = s_part[(size_t)row * CT_NUM + ctb];
    float M = fmaxf(m, mj);
    s = s * __expf(m - M) + sj * __expf(mj - M);
    m = M;
  }
#pragma unroll
  for (int off = 1; off < 64; off <<= 1) {
    float mo = __shfl_xor(m, off, 64);
    float so = __shfl_xor(s, off, 64);
    float M = fmaxf(m, mo);
    s = s * __expf(m - M) + so * __expf(mo - M);
    m = M;
  }
  float lse = m + logf(s);
  int tgt = target[row];
  bool valid = (tgt != IGNORE_INDEX);
  int st = valid ? tgt : 0;
  const float* xr = x + (size_t)row * H_DIM;
  const bf16_t* wrow = wT + (size_t)st * H_DIM;
  float t = 0.f;
  for (int k = l; k < H_DIM; k += 64)
    t += xr[k] * (float)wrow[k];
#pragma unroll
  for (int off = 1; off < 64; off <<= 1)
    t += __shfl_xor(t, off, 64);
  if (l == 0) {
    red[wv * 2]     = valid ? (lse - t) : 0.f;
    red[wv * 2 + 1] = valid ? lse : 0.f;
  }
  __syncthreads();
  if (threadIdx.x == 0) {
    blk_part[blockIdx.x * 2]     = red[0] + red[2] + red[4] + red[6];
    blk_part[blockIdx.x * 2 + 1] = red[1] + red[3] + red[5] + red[7];
  }
}

// ------------- final single-block reduce (no atomics, deterministic) -------
__global__ __launch_bounds__(256) void k_final(const float* __restrict__ bp,
                                               float* __restrict__ out) {
  __shared__ float ra[4], rb[4];
  float a = 0.f, b = 0.f;
  for (int i = threadIdx.x; i < N_ROWS / 4; i += 256) {
    a += bp[i * 2];
    b += bp[i * 2 + 1];
  }
#pragma unroll
  for (int off = 1; off < 64; off <<= 1) {
    a += __shfl_xor(a, off, 64);
    b += __shfl_xor(b, off, 64);
  }
  if ((threadIdx.x & 63) == 0) { ra[threadIdx.x >> 6] = a; rb[threadIdx.x >> 6] = b; }
  __syncthreads();
  if (threadIdx.x == 0) {
    out[0] = ra[0] + ra[1] + ra[2] + ra[3];
    out[1] = rb[0] + rb[1] + rb[2] + rb[3];
  }
}

extern "C" void kernel_launch(void* const* d_in, const int* in_sizes, int n_in,
                              void* d_out, int out_size, void* d_ws, size_t ws_size,
                              hipStream_t stream) {
  const float* x = (const float*)d_in[0];
  const float* w = (const float*)d_in[1];
  const int* target = (const int*)d_in[2];
  float* out = (float*)d_out;

  char* ws = (char*)d_ws;
  // ws layout:
  //   x_bf16   : 4096*1024*2  =  8,388,608
  //   wT       : 32000*1024*2 = 65,536,000
  //   m_part   : 4096*250*4   =  4,096,000
  //   s_part   : 4096*250*4   =  4,096,000
  //   blk_part : 1024*2*4     =      8,192
  bf16_t* x_bf = (bf16_t*)ws;
  bf16_t* wT = (bf16_t*)(ws + 8388608);
  float* m_part = (float*)(ws + 8388608 + 65536000);
  float* s_part = (float*)(ws + 8388608 + 65536000 + 4096000);
  float* blk_part = (float*)(ws + 8388608 + 65536000 + 4096000 + 4096000);

  k_cast_x<<<dim3(N_ROWS * H_DIM / (256 * 4)), 256, 0, stream>>>(x, x_bf);
  k_cast_wT<<<dim3(V_DIM / TV, H_DIM / TK), 256, 0, stream>>>(w, wT);
  k_gemm_lse<<<dim3(RT_NUM, CT_NUM), 256, 0, stream>>>(x_bf, wT, m_part, s_part);
  k_combine<<<dim3(N_ROWS / 4), 256, 0, stream>>>(x, wT, target, m_part, s_part, blk_part);
  k_final<<<dim3(1), 256, 0, stream>>>(blk_part, out);
}

// Round 3
// 609.562 us; speedup vs baseline: 1.2647x; 1.2647x over previous
//
#include <hip/hip_runtime.h>
#include <hip/hip_bf16.h>

typedef __bf16 bf16_t;
typedef __bf16 bf16x4 __attribute__((ext_vector_type(4)));
typedef __bf16 bf16x8 __attribute__((ext_vector_type(8)));
typedef float f32x4 __attribute__((ext_vector_type(4)));

#define IGNORE_INDEX (-100)
#define N_ROWS 4096
#define H_DIM  1024
#define V_DIM  32000

#define BM 128
#define BN 128
#define BK 32
#define CT_NUM (V_DIM / BN)   /* 250 */
#define RT_NUM (N_ROWS / BM)  /* 32 */

// ---------- fused prep: cast x (blocks 0..4095) + transpose-cast w ----------
#define TK 64
#define TV 64
#define XBLOCKS (N_ROWS * H_DIM / (256 * 4))  /* 4096 */
__global__ __launch_bounds__(256) void k_prep(const float* __restrict__ x,
                                              const float* __restrict__ w,
                                              bf16_t* __restrict__ x_bf,
                                              bf16_t* __restrict__ wT) {
  __shared__ float tile[TK][TV + 1];
  const int t = threadIdx.x;
  if (blockIdx.x < XBLOCKS) {
    int i = (blockIdx.x * 256 + t) * 4;
    float4 v = *(const float4*)(x + i);
    bf16x4 o = { (bf16_t)v.x, (bf16_t)v.y, (bf16_t)v.z, (bf16_t)v.w };
    *(bf16x4*)(x_bf + i) = o;
    return;
  }
  const int b = blockIdx.x - XBLOCKS;
  const int v0 = (b % (V_DIM / TV)) * TV;
  const int k0 = (b / (V_DIM / TV)) * TK;
  {
    const int vq = t & 15;        // float4 index within row
    const int kr0 = t >> 4;       // 0..15
#pragma unroll
    for (int r = 0; r < TK; r += 16) {
      float4 v = *(const float4*)(w + (size_t)(k0 + kr0 + r) * V_DIM + v0 + vq * 4);
      tile[kr0 + r][vq * 4 + 0] = v.x;
      tile[kr0 + r][vq * 4 + 1] = v.y;
      tile[kr0 + r][vq * 4 + 2] = v.z;
      tile[kr0 + r][vq * 4 + 3] = v.w;
    }
  }
  __syncthreads();
  {
    const int kq = t & 7;         // bf16x8 index within k-row
    const int vr0 = t >> 3;       // 0..31
#pragma unroll
    for (int r = 0; r < TV; r += 32) {
      bf16x8 o;
#pragma unroll
      for (int j = 0; j < 8; ++j)
        o[j] = (bf16_t)tile[kq * 8 + j][vr0 + r];
      *(bf16x8*)(wT + (size_t)(v0 + vr0 + r) * H_DIM + k0 + kq * 8) = o;
    }
  }
}

// ------------- fused GEMM tile + per-row max/sumexp partials -------------
// LDS layout: 16B slot s holds global (row = s>>2, kchunk = (s&3)^((s>>3)&3)).
//  - staging: slot = lane (global_load_lds constraint); each 4-lane group
//    covers one full 64B row segment (chunks XOR-permuted within the line)
//    -> same merged-request pattern as plain row-major.
//  - fragment read: lane l (r15=l&15, q=l>>4) reads slot r15*4 + (q^((r15>>1)&3));
//    every contiguous 8-lane group hits all 8 quad-bank groups once -> no
//    bank conflicts (16-lane groups exactly 2-way, which is free).
__global__ __launch_bounds__(256) void k_gemm_lse(const bf16_t* __restrict__ A,
                                                  const bf16_t* __restrict__ Bt,
                                                  float* __restrict__ m_part,
                                                  float* __restrict__ s_part) {
  __shared__ __align__(16) bf16_t sA[BM * BK];
  __shared__ __align__(16) bf16_t sB[BN * BK];
  __shared__ float maxbuf[BM][2];
  __shared__ float sumbuf[BM][2];

  const int tid = threadIdx.x;
  const int rt = blockIdx.x;   // 0..31  row tile (fast dim -> per-XCD A stays hot)
  const int ct = blockIdx.y;   // 0..249 column tile
  const int m0 = rt * BM;
  const int n0 = ct * BN;

  const int w = tid >> 6;
  const int l = tid & 63;
  const int wr = w >> 1, wc = w & 1;
  const int quad = l >> 4, lc = l & 15;

  f32x4 acc[4][4];
#pragma unroll
  for (int i = 0; i < 4; ++i)
#pragma unroll
    for (int j = 0; j < 4; ++j)
      acc[i][j] = (f32x4){0.f, 0.f, 0.f, 0.f};

  // staging: slot s=tid and s=tid+256
  const int r0 = tid >> 2;                              // rows 0..63
  const int c0 = ((tid & 3) ^ ((tid >> 3) & 3)) * 8;    // swizzled k-chunk
  const int r1 = r0 + 64;                               // ((tid+256)>>3)&3 == (tid>>3)&3

  const bf16_t* a0 = A + (size_t)(m0 + r0) * H_DIM + c0;
  const bf16_t* a1 = A + (size_t)(m0 + r1) * H_DIM + c0;
  const bf16_t* b0 = Bt + (size_t)(n0 + r0) * H_DIM + c0;
  const bf16_t* b1 = Bt + (size_t)(n0 + r1) * H_DIM + c0;
  bf16_t* dA0 = sA + (size_t)tid * 8;
  bf16_t* dA1 = sA + (size_t)(tid + 256) * 8;
  bf16_t* dB0 = sB + (size_t)tid * 8;
  bf16_t* dB1 = sB + (size_t)(tid + 256) * 8;

  // fragment read offsets (elements): ((g*16 + r15)*4 + (q ^ ((r15>>1)&3))) * 8
  const int swz = (quad ^ ((lc >> 1) & 3));
  const int fbase = (lc * 4 + swz) * 8;   // within a 16-row group (64 slots)

  for (int kt = 0; kt < H_DIM / BK; ++kt) {
    __syncthreads();  // previous iter's ds_reads done before overwrite
    __builtin_amdgcn_global_load_lds((const __attribute__((address_space(1))) void*)a0,
                                     (__attribute__((address_space(3))) void*)dA0, 16, 0, 0);
    __builtin_amdgcn_global_load_lds((const __attribute__((address_space(1))) void*)a1,
                                     (__attribute__((address_space(3))) void*)dA1, 16, 0, 0);
    __builtin_amdgcn_global_load_lds((const __attribute__((address_space(1))) void*)b0,
                                     (__attribute__((address_space(3))) void*)dB0, 16, 0, 0);
    __builtin_amdgcn_global_load_lds((const __attribute__((address_space(1))) void*)b1,
                                     (__attribute__((address_space(3))) void*)dB1, 16, 0, 0);
    a0 += BK; a1 += BK; b0 += BK; b1 += BK;
    __syncthreads();  // drains vmcnt for all waves

    bf16x8 a_frag[4], b_frag[4];
#pragma unroll
    for (int i = 0; i < 4; ++i)
      a_frag[i] = *(const bf16x8*)(sA + (size_t)((wr * 4 + i) * 512 + fbase));
#pragma unroll
    for (int j = 0; j < 4; ++j)
      b_frag[j] = *(const bf16x8*)(sB + (size_t)((wc * 4 + j) * 512 + fbase));
#pragma unroll
    for (int i = 0; i < 4; ++i)
#pragma unroll
      for (int j = 0; j < 4; ++j)
        acc[i][j] = __builtin_amdgcn_mfma_f32_16x16x32_bf16(a_frag[i], b_frag[j], acc[i][j], 0, 0, 0);
  }

  // C/D layout: col = lane&15 (N-dim), row = quad*4 + reg (M-dim).
  // Global row of acc[i][*][r] = m0 + wr*64 + i*16 + quad*4 + r
  float rmax[4][4];
#pragma unroll
  for (int i = 0; i < 4; ++i)
#pragma unroll
    for (int r = 0; r < 4; ++r) {
      float mx = fmaxf(fmaxf(acc[i][0][r], acc[i][1][r]),
                       fmaxf(acc[i][2][r], acc[i][3][r]));
#pragma unroll
      for (int off = 1; off < 16; off <<= 1)
        mx = fmaxf(mx, __shfl_xor(mx, off, 64));
      rmax[i][r] = mx;
    }
  __syncthreads();
  if (lc == 0) {
#pragma unroll
    for (int i = 0; i < 4; ++i)
#pragma unroll
      for (int r = 0; r < 4; ++r)
        maxbuf[wr * 64 + i * 16 + quad * 4 + r][wc] = rmax[i][r];
  }
  __syncthreads();
  float rowmax[4][4];
#pragma unroll
  for (int i = 0; i < 4; ++i)
#pragma unroll
    for (int r = 0; r < 4; ++r) {
      int row = wr * 64 + i * 16 + quad * 4 + r;
      rowmax[i][r] = fmaxf(maxbuf[row][0], maxbuf[row][1]);
    }
#pragma unroll
  for (int i = 0; i < 4; ++i)
#pragma unroll
    for (int r = 0; r < 4; ++r) {
      float s = __expf(acc[i][0][r] - rowmax[i][r]) + __expf(acc[i][1][r] - rowmax[i][r]) +
                __expf(acc[i][2][r] - rowmax[i][r]) + __expf(acc[i][3][r] - rowmax[i][r]);
#pragma unroll
      for (int off = 1; off < 16; off <<= 1)
        s += __shfl_xor(s, off, 64);
      if (lc == 0) sumbuf[wr * 64 + i * 16 + quad * 4 + r][wc] = s;
    }
  __syncthreads();
  if (wc == 0 && lc == 0) {
#pragma unroll
    for (int i = 0; i < 4; ++i)
#pragma unroll
      for (int r = 0; r < 4; ++r) {
        int row = wr * 64 + i * 16 + quad * 4 + r;
        size_t idx = (size_t)(m0 + row) * CT_NUM + ct;
        m_part[idx] = rowmax[i][r];
        s_part[idx] = sumbuf[row][0] + sumbuf[row][1];
      }
  }
}

// ------------- combine partials + target logit -> per-block partial sums ----
__global__ __launch_bounds__(256) void k_combine(const float* __restrict__ x,
                                                 const bf16_t* __restrict__ wT,
                                                 const int* __restrict__ target,
                                                 const float* __restrict__ m_part,
                                                 const float* __restrict__ s_part,
                                                 float* __restrict__ blk_part) {
  __shared__ float red[8];
  const int wv = threadIdx.x >> 6;
  const int row = blockIdx.x * 4 + wv;  // one wave per row
  const int l = threadIdx.x & 63;
  float m = -INFINITY, s = 0.f;
  for (int ctb = l; ctb < CT_NUM; ctb += 64) {
    float mj = m_part[(size_t)row * CT_NUM + ctb];
    float sj = s_part[(size_t)row * CT_NUM + ctb];
    float M = fmaxf(m, mj);
    s = s * __expf(m - M) + sj * __expf(mj - M);
    m = M;
  }
#pragma unroll
  for (int off = 1; off < 64; off <<= 1) {
    float mo = __shfl_xor(m, off, 64);
    float so = __shfl_xor(s, off, 64);
    float M = fmaxf(m, mo);
    s = s * __expf(m - M) + so * __expf(mo - M);
    m = M;
  }
  float lse = m + logf(s);
  int tgt = target[row];
  bool valid = (tgt != IGNORE_INDEX);
  int st = valid ? tgt : 0;
  const float* xr = x + (size_t)row * H_DIM;
  const bf16_t* wrow = wT + (size_t)st * H_DIM;
  float t = 0.f;
  for (int k = l; k < H_DIM; k += 64)
    t += xr[k] * (float)wrow[k];
#pragma unroll
  for (int off = 1; off < 64; off <<= 1)
    t += __shfl_xor(t, off, 64);
  if (l == 0) {
    red[wv * 2]     = valid ? (lse - t) : 0.f;
    red[wv * 2 + 1] = valid ? lse : 0.f;
  }
  __syncthreads();
  if (threadIdx.x == 0) {
    blk_part[blockIdx.x * 2]     = red[0] + red[2] + red[4] + red[6];
    blk_part[blockIdx.x * 2 + 1] = red[1] + red[3] + red[5] + red[7];
  }
}

// ------------- final single-block reduce (no atomics, deterministic) -------
__global__ __launch_bounds__(256) void k_final(const float* __restrict__ bp,
                                               float* __restrict__ out) {
  __shared__ float ra[4], rb[4];
  float a = 0.f, b = 0.f;
  for (int i = threadIdx.x; i < N_ROWS / 4; i += 256) {
    a += bp[i * 2];
    b += bp[i * 2 + 1];
  }
#pragma unroll
  for (int off = 1; off < 64; off <<= 1) {
    a += __shfl_xor(a, off, 64);
    b += __shfl_xor(b, off, 64);
  }
  if ((threadIdx.x & 63) == 0) { ra[threadIdx.x >> 6] = a; rb[threadIdx.x >> 6] = b; }
  __syncthreads();
  if (threadIdx.x == 0) {
    out[0] = ra[0] + ra[1] + ra[2] + ra[3];
    out[1] = rb[0] + rb[1] + rb[2] + rb[3];
  }
}

extern "C" void kernel_launch(void* const* d_in, const int* in_sizes, int n_in,
                              void* d_out, int out_size, void* d_ws, size_t ws_size,
                              hipStream_t stream) {
  const float* x = (const float*)d_in[0];
  const float* w = (const float*)d_in[1];
  const int* target = (const int*)d_in[2];
  float* out = (float*)d_out;

  char* ws = (char*)d_ws;
  // ws layout:
  //   x_bf16   : 4096*1024*2  =  8,388,608
  //   wT       : 32000*1024*2 = 65,536,000
  //   m_part   : 4096*250*4   =  4,096,000
  //   s_part   : 4096*250*4   =  4,096,000
  //   blk_part : 1024*2*4     =      8,192
  bf16_t* x_bf = (bf16_t*)ws;
  bf16_t* wT = (bf16_t*)(ws + 8388608);
  float* m_part = (float*)(ws + 8388608 + 65536000);
  float* s_part = (float*)(ws + 8388608 + 65536000 + 4096000);
  float* blk_part = (float*)(ws + 8388608 + 65536000 + 4096000 + 4096000);

  k_prep<<<dim3(XBLOCKS + (V_DIM / TV) * (H_DIM / TK)), 256, 0, stream>>>(x, w, x_bf, wT);
  k_gemm_lse<<<dim3(RT_NUM, CT_NUM), 256, 0, stream>>>(x_bf, wT, m_part, s_part);
  k_combine<<<dim3(N_ROWS / 4), 256, 0, stream>>>(x, wT, target, m_part, s_part, blk_part);
  k_final<<<dim3(1), 256, 0, stream>>>(blk_part, out);
}

// Round 4
// 445.874 us; speedup vs baseline: 1.7290x; 1.3671x over previous
//
#include <hip/hip_runtime.h>
#include <hip/hip_bf16.h>

typedef float f32x4 __attribute__((ext_vector_type(4)));
typedef int i32x4v __attribute__((ext_vector_type(4)));
typedef int i32x8v __attribute__((ext_vector_type(8)));

#define IGNORE_INDEX (-100)
#define N_ROWS 4096
#define H_DIM  1024
#define V_DIM  32000

#define BM 128
#define BN 128
#define BK 128                 /* fp8 elements = bytes */
#define CT_NUM (V_DIM / BN)    /* 250 */
#define RT_NUM (N_ROWS / BM)   /* 32 */
#define SCALE1 0x7f7f7f7f      /* 4x e8m0 = 127 -> x1.0 */

// ---------- fused prep: cast x -> fp8 (blocks < XB8) + transpose-cast w ----------
#define XB8 (N_ROWS * H_DIM / (256 * 16))  /* 1024 */
__global__ __launch_bounds__(256) void k_prep(const float* __restrict__ x,
                                              const float* __restrict__ w,
                                              unsigned char* __restrict__ x8,
                                              unsigned char* __restrict__ wT8) {
  __shared__ float tile[128][33];
  const int t = threadIdx.x;
  if (blockIdx.x < XB8) {
    size_t i = ((size_t)blockIdx.x * 256 + t) * 16;
    const float4* xp = (const float4*)(x + i);
    float4 f0 = xp[0], f1 = xp[1], f2 = xp[2], f3 = xp[3];
    int4 o;
    int r;
    r = __builtin_amdgcn_cvt_pk_fp8_f32(f0.x, f0.y, 0, false);
    r = __builtin_amdgcn_cvt_pk_fp8_f32(f0.z, f0.w, r, true);
    o.x = r;
    r = __builtin_amdgcn_cvt_pk_fp8_f32(f1.x, f1.y, 0, false);
    r = __builtin_amdgcn_cvt_pk_fp8_f32(f1.z, f1.w, r, true);
    o.y = r;
    r = __builtin_amdgcn_cvt_pk_fp8_f32(f2.x, f2.y, 0, false);
    r = __builtin_amdgcn_cvt_pk_fp8_f32(f2.z, f2.w, r, true);
    o.z = r;
    r = __builtin_amdgcn_cvt_pk_fp8_f32(f3.x, f3.y, 0, false);
    r = __builtin_amdgcn_cvt_pk_fp8_f32(f3.z, f3.w, r, true);
    o.w = r;
    *(int4*)(x8 + i) = o;
    return;
  }
  // transpose-cast: 128(k) x 32(v) tile
  const int b = blockIdx.x - XB8;
  const int v0 = (b % (V_DIM / 32)) * 32;
  const int k0 = (b / (V_DIM / 32)) * 128;
  {
    const int vq = t & 7;     // float4 index (8 x 4 = 32 floats/row)
    const int kr = t >> 3;    // 0..31
#pragma unroll
    for (int p = 0; p < 128; p += 32) {
      float4 v = *(const float4*)(w + (size_t)(k0 + kr + p) * V_DIM + v0 + vq * 4);
      tile[kr + p][vq * 4 + 0] = v.x;
      tile[kr + p][vq * 4 + 1] = v.y;
      tile[kr + p][vq * 4 + 2] = v.z;
      tile[kr + p][vq * 4 + 3] = v.w;
    }
  }
  __syncthreads();
  {
    const int kq = t & 7;     // int4 index within 128B k-run
    const int vr = t >> 3;    // 0..31
    int4 o;
    int r;
#pragma unroll
    for (int d = 0; d < 4; ++d) {
      r = __builtin_amdgcn_cvt_pk_fp8_f32(tile[kq * 16 + d * 4 + 0][vr],
                                          tile[kq * 16 + d * 4 + 1][vr], 0, false);
      r = __builtin_amdgcn_cvt_pk_fp8_f32(tile[kq * 16 + d * 4 + 2][vr],
                                          tile[kq * 16 + d * 4 + 3][vr], r, true);
      ((int*)&o)[d] = r;
    }
    *(int4*)(wT8 + (size_t)(v0 + vr) * H_DIM + k0 + kq * 16) = o;
  }
}

// ------------- fused MX-fp8 GEMM tile + per-row max/sumexp partials -------------
// LDS layout per operand (16KB): 16B slot s holds (row = s>>3, chunk c where
// chunk-position (s&7) = c ^ (row&7)). Staging: slot = issue*256 + tid; each
// 8-lane group covers one full 128B row segment (XOR-permuted within the line).
// Fragment (16x16x128 fp8): lane (r15=l&15, q=l>>4) holds A[r15][q*32+0..31]
// = chunks 2q, 2q+1 of row r15 -> two ds_read_b128 at
//   row*128 + ((2q+h)^(r15&7))*16.  Bank-quad = (2q+h)^(r15&7): exactly 8
// lanes per quad -> uniform, conflict-free.
__global__ __launch_bounds__(256) void k_gemm_lse(const unsigned char* __restrict__ A,
                                                  const unsigned char* __restrict__ Bt,
                                                  float* __restrict__ m_part,
                                                  float* __restrict__ s_part) {
  __shared__ __align__(16) unsigned char sA[BM * BK];
  __shared__ __align__(16) unsigned char sB[BN * BK];
  __shared__ float maxbuf[BM][2];
  __shared__ float sumbuf[BM][2];

  const int tid = threadIdx.x;
  const int rt = blockIdx.x;   // fast dim -> per-XCD A stays hot
  const int ct = blockIdx.y;
  const int m0 = rt * BM;
  const int n0 = ct * BN;

  const int w = tid >> 6;
  const int l = tid & 63;
  const int wr = w >> 1, wc = w & 1;
  const int quad = l >> 4, lc = l & 15;

  f32x4 acc[4][4];
#pragma unroll
  for (int i = 0; i < 4; ++i)
#pragma unroll
    for (int j = 0; j < 4; ++j)
      acc[i][j] = (f32x4){0.f, 0.f, 0.f, 0.f};

  // staging addresses (issue i adds 32 rows / 4096 LDS bytes)
  const int srow = tid >> 3;                               // 0..31
  const int scol = ((tid & 7) ^ ((tid >> 3) & 7)) * 16;    // swizzled 16B chunk
  const unsigned char* ga = A + (size_t)(m0 + srow) * H_DIM + scol;
  const unsigned char* gb = Bt + (size_t)(n0 + srow) * H_DIM + scol;
  unsigned char* da = sA + tid * 16;
  unsigned char* db = sB + tid * 16;

  // fragment read offsets
  const int base_r = lc * 128;
  const int sw0 = ((quad * 2) ^ (lc & 7)) * 16;
  const int sw1 = ((quad * 2 + 1) ^ (lc & 7)) * 16;

  for (int kt = 0; kt < H_DIM / BK; ++kt) {
    __syncthreads();  // previous iter's ds_reads done before overwrite
#pragma unroll
    for (int i = 0; i < 4; ++i) {
      __builtin_amdgcn_global_load_lds(
          (const __attribute__((address_space(1))) void*)(ga + (size_t)i * 32 * H_DIM),
          (__attribute__((address_space(3))) void*)(da + i * 4096), 16, 0, 0);
      __builtin_amdgcn_global_load_lds(
          (const __attribute__((address_space(1))) void*)(gb + (size_t)i * 32 * H_DIM),
          (__attribute__((address_space(3))) void*)(db + i * 4096), 16, 0, 0);
    }
    ga += BK; gb += BK;
    __syncthreads();  // drains vmcnt for all waves

    i32x8v a_frag[4], b_frag[4];
#pragma unroll
    for (int i = 0; i < 4; ++i) {
      const unsigned char* p = sA + (wr * 4 + i) * 2048 + base_r;
      i32x4v lo = *(const i32x4v*)(p + sw0);
      i32x4v hi = *(const i32x4v*)(p + sw1);
      a_frag[i] = __builtin_shufflevector(lo, hi, 0, 1, 2, 3, 4, 5, 6, 7);
    }
#pragma unroll
    for (int j = 0; j < 4; ++j) {
      const unsigned char* p = sB + (wc * 4 + j) * 2048 + base_r;
      i32x4v lo = *(const i32x4v*)(p + sw0);
      i32x4v hi = *(const i32x4v*)(p + sw1);
      b_frag[j] = __builtin_shufflevector(lo, hi, 0, 1, 2, 3, 4, 5, 6, 7);
    }
#pragma unroll
    for (int i = 0; i < 4; ++i)
#pragma unroll
      for (int j = 0; j < 4; ++j)
        acc[i][j] = __builtin_amdgcn_mfma_scale_f32_16x16x128_f8f6f4(
            a_frag[i], b_frag[j], acc[i][j], 0, 0, 0, SCALE1, 0, SCALE1);
  }

  // C/D layout (shape-determined): col = lane&15, row = quad*4 + reg.
  float rmax[4][4];
#pragma unroll
  for (int i = 0; i < 4; ++i)
#pragma unroll
    for (int r = 0; r < 4; ++r) {
      float mx = fmaxf(fmaxf(acc[i][0][r], acc[i][1][r]),
                       fmaxf(acc[i][2][r], acc[i][3][r]));
#pragma unroll
      for (int off = 1; off < 16; off <<= 1)
        mx = fmaxf(mx, __shfl_xor(mx, off, 64));
      rmax[i][r] = mx;
    }
  __syncthreads();
  if (lc == 0) {
#pragma unroll
    for (int i = 0; i < 4; ++i)
#pragma unroll
      for (int r = 0; r < 4; ++r)
        maxbuf[wr * 64 + i * 16 + quad * 4 + r][wc] = rmax[i][r];
  }
  __syncthreads();
  float rowmax[4][4];
#pragma unroll
  for (int i = 0; i < 4; ++i)
#pragma unroll
    for (int r = 0; r < 4; ++r) {
      int row = wr * 64 + i * 16 + quad * 4 + r;
      rowmax[i][r] = fmaxf(maxbuf[row][0], maxbuf[row][1]);
    }
#pragma unroll
  for (int i = 0; i < 4; ++i)
#pragma unroll
    for (int r = 0; r < 4; ++r) {
      float s = __expf(acc[i][0][r] - rowmax[i][r]) + __expf(acc[i][1][r] - rowmax[i][r]) +
                __expf(acc[i][2][r] - rowmax[i][r]) + __expf(acc[i][3][r] - rowmax[i][r]);
#pragma unroll
      for (int off = 1; off < 16; off <<= 1)
        s += __shfl_xor(s, off, 64);
      if (lc == 0) sumbuf[wr * 64 + i * 16 + quad * 4 + r][wc] = s;
    }
  __syncthreads();
  if (wc == 0 && lc == 0) {
#pragma unroll
    for (int i = 0; i < 4; ++i)
#pragma unroll
      for (int r = 0; r < 4; ++r) {
        int row = wr * 64 + i * 16 + quad * 4 + r;
        size_t idx = (size_t)(m0 + row) * CT_NUM + ct;
        m_part[idx] = rowmax[i][r];
        s_part[idx] = sumbuf[row][0] + sumbuf[row][1];
      }
  }
}

// ------------- combine partials + target logit -> per-block partial sums ----
__global__ __launch_bounds__(256) void k_combine(const float* __restrict__ x,
                                                 const unsigned char* __restrict__ wT8,
                                                 const int* __restrict__ target,
                                                 const float* __restrict__ m_part,
                                                 const float* __restrict__ s_part,
                                                 float* __restrict__ blk_part) {
  __shared__ float red[8];
  const int wv = threadIdx.x >> 6;
  const int row = blockIdx.x * 4 + wv;  // one wave per row
  const int l = threadIdx.x & 63;
  float m = -INFINITY, s = 0.f;
  for (int ctb = l; ctb < CT_NUM; ctb += 64) {
    float mj = m_part[(size_t)row * CT_NUM + ctb];
    float sj = s_part[(size_t)row * CT_NUM + ctb];
    float M = fmaxf(m, mj);
    s = s * __expf(m - M) + sj * __expf(mj - M);
    m = M;
  }
#pragma unroll
  for (int off = 1; off < 64; off <<= 1) {
    float mo = __shfl_xor(m, off, 64);
    float so = __shfl_xor(s, off, 64);
    float M = fmaxf(m, mo);
    s = s * __expf(m - M) + so * __expf(mo - M);
    m = M;
  }
  float lse = m + logf(s);
  int tgt = target[row];
  bool valid = (tgt != IGNORE_INDEX);
  int st = valid ? tgt : 0;
  // target logit: x[row] fp32 . wT8[st] fp8 (16 bytes per lane)
  const float* xr = x + (size_t)row * H_DIM + l * 16;
  int4 wv4 = *(const int4*)(wT8 + (size_t)st * H_DIM + l * 16);
  float t = 0.f;
#define ACC_DW(dw, base)                                              \
  t += xr[base + 0] * __builtin_amdgcn_cvt_f32_fp8(dw, 0);            \
  t += xr[base + 1] * __builtin_amdgcn_cvt_f32_fp8(dw, 1);            \
  t += xr[base + 2] * __builtin_amdgcn_cvt_f32_fp8(dw, 2);            \
  t += xr[base + 3] * __builtin_amdgcn_cvt_f32_fp8(dw, 3);
  ACC_DW(wv4.x, 0)
  ACC_DW(wv4.y, 4)
  ACC_DW(wv4.z, 8)
  ACC_DW(wv4.w, 12)
#undef ACC_DW
#pragma unroll
  for (int off = 1; off < 64; off <<= 1)
    t += __shfl_xor(t, off, 64);
  if (l == 0) {
    red[wv * 2]     = valid ? (lse - t) : 0.f;
    red[wv * 2 + 1] = valid ? lse : 0.f;
  }
  __syncthreads();
  if (threadIdx.x == 0) {
    blk_part[blockIdx.x * 2]     = red[0] + red[2] + red[4] + red[6];
    blk_part[blockIdx.x * 2 + 1] = red[1] + red[3] + red[5] + red[7];
  }
}

// ------------- final single-block reduce -------
__global__ __launch_bounds__(256) void k_final(const float* __restrict__ bp,
                                               float* __restrict__ out) {
  __shared__ float ra[4], rb[4];
  float a = 0.f, b = 0.f;
  for (int i = threadIdx.x; i < N_ROWS / 4; i += 256) {
    a += bp[i * 2];
    b += bp[i * 2 + 1];
  }
#pragma unroll
  for (int off = 1; off < 64; off <<= 1) {
    a += __shfl_xor(a, off, 64);
    b += __shfl_xor(b, off, 64);
  }
  if ((threadIdx.x & 63) == 0) { ra[threadIdx.x >> 6] = a; rb[threadIdx.x >> 6] = b; }
  __syncthreads();
  if (threadIdx.x == 0) {
    out[0] = ra[0] + ra[1] + ra[2] + ra[3];
    out[1] = rb[0] + rb[1] + rb[2] + rb[3];
  }
}

extern "C" void kernel_launch(void* const* d_in, const int* in_sizes, int n_in,
                              void* d_out, int out_size, void* d_ws, size_t ws_size,
                              hipStream_t stream) {
  const float* x = (const float*)d_in[0];
  const float* w = (const float*)d_in[1];
  const int* target = (const int*)d_in[2];
  float* out = (float*)d_out;

  char* ws = (char*)d_ws;
  // ws layout:
  //   x8       : 4096*1024   =  4,194,304
  //   wT8      : 32000*1024  = 32,768,000
  //   m_part   : 4096*250*4  =  4,096,000
  //   s_part   : 4096*250*4  =  4,096,000
  //   blk_part : 1024*2*4    =      8,192
  unsigned char* x8 = (unsigned char*)ws;
  unsigned char* wT8 = (unsigned char*)(ws + 4194304);
  float* m_part = (float*)(ws + 4194304 + 32768000);
  float* s_part = (float*)(ws + 4194304 + 32768000 + 4096000);
  float* blk_part = (float*)(ws + 4194304 + 32768000 + 4096000 + 4096000);

  k_prep<<<dim3(XB8 + (V_DIM / 32) * (H_DIM / 128)), 256, 0, stream>>>(x, w, x8, wT8);
  k_gemm_lse<<<dim3(RT_NUM, CT_NUM), 256, 0, stream>>>(x8, wT8, m_part, s_part);
  k_combine<<<dim3(N_ROWS / 4), 256, 0, stream>>>(x, wT8, target, m_part, s_part, blk_part);
  k_final<<<dim3(1), 256, 0, stream>>>(blk_part, out);
}